// Round 6
// baseline (453.827 us; speedup 1.0000x reference)
//
#include <hip/hip_runtime.h>
#include <hip/hip_fp16.h>

typedef _Float16 f16;
typedef __attribute__((ext_vector_type(8))) _Float16 f16x8;
typedef __attribute__((ext_vector_type(4))) _Float16 f16x4;
typedef __attribute__((ext_vector_type(4))) float f32x4;

#define BM 256
#define BN 256
#define BK 64

__device__ __forceinline__ void gll16(const void* src, void* dst) {
  __builtin_amdgcn_global_load_lds((const __attribute__((address_space(1))) void*)src,
                                   (__attribute__((address_space(3))) void*)dst,
                                   16, 0, 0);
}

// C[m,n] = sum_k A[m,k] * B[n,k]  ("BT" form). 8-phase m201-style schedule (R5).
// CVT=false: operands fp16, staged via global_load_lds, counted vmcnt(4) at ph4/ph8.
// CVT=true:  operands fp32, staged via reg (2x dwordx4 -> v_cvt -> ds_write_b128),
//            SAME LDS layout + source swizzle (read path identical). ds_writes are
//            drained by each phase's own lgkmcnt(0), one barrier before any reader
//            (strictly earlier publication than the gll path) -> no vmcnt needed.
// Swizzle: linear slot s of row r holds global slot s^(r&7) (BK=64: row=128B drops
// out of bank index; measured 0 conflicts R3/R5).
// MODE 0: C fp16   MODE 1: P=exp(acc*scale+mask) fp16 + row-sum partials
// MODE 2: C fp32 = acc / lvec[z*M+row]
template<int MODE, bool CVT>
__global__ __launch_bounds__(512, 2)
void gemm_bt(const void* __restrict__ Aall, const void* __restrict__ Ball,
             void* __restrict__ Call,
             int M, int N, int K, int lda, int ldb, int ldc,
             long strideA, long strideB, long strideC,
             const float* __restrict__ maskAll, long strideMask,
             float* __restrict__ lvec, float scale)
{
  __shared__ __align__(16) f16 smA[2][BM * BK];   // 2 x 32 KB
  __shared__ __align__(16) f16 smB[2][BN * BK];   // 2 x 32 KB  -> 128 KiB

  // T1: bijective XCD-aware remap (all grids have nwg % 8 == 0)
  unsigned gx = gridDim.x, gy = gridDim.y;
  unsigned id = (blockIdx.z * gy + blockIdx.y) * gx + blockIdx.x;
  unsigned nwg = gx * gy * gridDim.z;
  unsigned swz = (id & 7) * (nwg >> 3) + (id >> 3);
  unsigned bx = swz % gx, rem = swz / gx;
  unsigned by = rem % gy, bz = rem / gy;

  const int z = bz;
  const void* A = (const char*)Aall + (long)z * strideA * (CVT ? 4 : 2);
  const void* B = (const char*)Ball + (long)z * strideB * (CVT ? 4 : 2);

  const int tid  = threadIdx.x;
  const int wid  = tid >> 6;
  const int lane = tid & 63;
  const int wm = wid >> 2;        // 0..1 -> 128 rows of C
  const int wn = wid & 3;         // 0..3 -> 64 cols of C
  const int lr = lane & 15;
  const int g  = lane >> 4;       // k-slot 0..3 (8 f16 each)

  const long brow = (long)by * BM;
  const long bcol = (long)bx * BN;
  const int  nt   = K / BK;       // >= 4, even

  f32x4 acc[8][4] = {};
  f16x8 af[8], bf[8];

  // stage one 128-row half-tile (16 KB as f16, 2 chunks/thread).
  auto stage_half = [&](f16* dst, const void* srcBase, long prow, int ld_, int rowOff, int t) {
    #pragma unroll
    for (int i = 0; i < 2; ++i) {
      int c  = i * 512 + tid;
      int r  = c >> 3;
      int sl = (c & 7) ^ (r & 7);
      long off = (prow + rowOff + r) * (long)ld_ + t * BK + sl * 8;
      if constexpr (CVT) {
        const float* s = (const float*)srcBase + off;
        float4 lo = *(const float4*)s;
        float4 hi = *(const float4*)(s + 4);
        f16x8 o;
        o[0] = (f16)lo.x; o[1] = (f16)lo.y; o[2] = (f16)lo.z; o[3] = (f16)lo.w;
        o[4] = (f16)hi.x; o[5] = (f16)hi.y; o[6] = (f16)hi.z; o[7] = (f16)hi.w;
        *(f16x8*)(dst + rowOff * BK + c * 8) = o;
      } else {
        gll16((const f16*)srcBase + off, dst + rowOff * BK + c * 8);
      }
    }
  };
  auto rdA = [&](const f16* sa, int mh) {
    #pragma unroll
    for (int fm = 0; fm < 4; ++fm)
      #pragma unroll
      for (int ks = 0; ks < 2; ++ks) {
        int r = wm * 128 + mh * 64 + fm * 16 + lr;
        af[fm * 2 + ks] = *(const f16x8*)(sa + r * BK + ((ks * 4 + g) ^ (r & 7)) * 8);
      }
  };
  auto rdB = [&](const f16* sb, int nh) {
    #pragma unroll
    for (int fn = 0; fn < 2; ++fn)
      #pragma unroll
      for (int ks = 0; ks < 2; ++ks) {
        int r = wn * 64 + (nh * 2 + fn) * 16 + lr;
        bf[(nh * 2 + fn) * 2 + ks] = *(const f16x8*)(sb + r * BK + ((ks * 4 + g) ^ (r & 7)) * 8);
      }
  };
  auto sync_mfma = [&](int fm0, int fn0) {
    __builtin_amdgcn_s_barrier();
    asm volatile("s_waitcnt lgkmcnt(0)" ::: "memory");
    __builtin_amdgcn_sched_barrier(0);
    __builtin_amdgcn_s_setprio(1);
    #pragma unroll
    for (int fm = 0; fm < 4; ++fm)
      #pragma unroll
      for (int fn = 0; fn < 2; ++fn)
        #pragma unroll
        for (int ks = 0; ks < 2; ++ks)
          acc[fm0 + fm][fn0 + fn] = __builtin_amdgcn_mfma_f32_16x16x32_f16(
              af[fm * 2 + ks], bf[(fn0 + fn) * 2 + ks], acc[fm0 + fm][fn0 + fn], 0, 0, 0);
    __builtin_amdgcn_s_setprio(0);
    __builtin_amdgcn_s_barrier();
  };

  // prologue: tile0 (A,B) + tile1 B; A(1) staged in iter0 ph1/ph2.
  stage_half(smA[0], A, brow, lda, 0, 0);
  stage_half(smA[0], A, brow, lda, 128, 0);
  stage_half(smB[0], B, bcol, ldb, 0, 0);
  stage_half(smB[0], B, bcol, ldb, 128, 0);
  stage_half(smB[1], B, bcol, ldb, 0, 1);
  stage_half(smB[1], B, bcol, ldb, 128, 1);
  if constexpr (!CVT) { asm volatile("s_waitcnt vmcnt(4)" ::: "memory"); }
  else                { asm volatile("s_waitcnt lgkmcnt(0)" ::: "memory"); }
  __builtin_amdgcn_s_barrier();

  const int niter = nt / 2;
  for (int i = 0; i < niter; ++i) {
    const bool last = (i == niter - 1);
    const int t2 = 2 * i + 2, t3 = 2 * i + 3;

    // ph1: reads buf0 A-hi + B n0-1 ; stage A-hi(2i+1)
    rdA(smA[0], 0); rdB(smB[0], 0);
    stage_half(smA[1], A, brow, lda, 0, 2 * i + 1);
    sync_mfma(0, 0);
    // ph2: reads buf0 B n2-3 ; stage A-lo(2i+1)
    rdB(smB[0], 1);
    stage_half(smA[1], A, brow, lda, 128, 2 * i + 1);
    sync_mfma(0, 2);
    // ph3: reads buf0 A-lo ; stage B-hi(t2)
    rdA(smA[0], 1);
    if (t2 < nt) stage_half(smB[0], B, bcol, ldb, 0, t2);
    sync_mfma(4, 2);
    // ph4: stage B-lo(t2) ; counted wait (gll path only)
    if (t2 < nt) stage_half(smB[0], B, bcol, ldb, 128, t2);
    if constexpr (!CVT) {
      if (!last) { asm volatile("s_waitcnt vmcnt(4)" ::: "memory"); }
      else       { asm volatile("s_waitcnt vmcnt(0)" ::: "memory"); }
    }
    sync_mfma(4, 0);
    // ph5: reads buf1 A-hi + B n0-1 ; stage A-hi(t2)
    rdA(smA[1], 0); rdB(smB[1], 0);
    if (t2 < nt) stage_half(smA[0], A, brow, lda, 0, t2);
    sync_mfma(0, 0);
    // ph6: reads buf1 B n2-3 ; stage A-lo(t2)
    rdB(smB[1], 1);
    if (t2 < nt) stage_half(smA[0], A, brow, lda, 128, t2);
    sync_mfma(0, 2);
    // ph7: reads buf1 A-lo ; stage B-hi(t3)
    rdA(smA[1], 1);
    if (t3 < nt) stage_half(smB[1], B, bcol, ldb, 0, t3);
    sync_mfma(4, 2);
    // ph8: stage B-lo(t3) ; counted wait (gll path only)
    if (t3 < nt) stage_half(smB[1], B, bcol, ldb, 128, t3);
    if constexpr (!CVT) {
      if (!last) { asm volatile("s_waitcnt vmcnt(4)" ::: "memory"); }
    }
    sync_mfma(4, 0);
  }

  // C/D layout (m89-verified): col = lane&15, row = (lane>>4)*4 + reg
  const int rb = (lane >> 4) * 4;

  if (MODE == 0) {
    f16* C = (f16*)Call + (long)z * strideC;
    #pragma unroll
    for (int m = 0; m < 8; ++m)
      #pragma unroll
      for (int j = 0; j < 4; ++j) {
        long grow = brow + wm * 128 + m * 16 + rb + j;
        #pragma unroll
        for (int n = 0; n < 4; ++n) {
          long gcol = bcol + wn * 64 + n * 16 + lr;
          C[grow * ldc + gcol] = (f16)acc[m][n][j];
        }
      }
  } else if (MODE == 1) {
    f16* C = (f16*)Call + (long)z * strideC;
    const float* mask = maskAll + (long)z * strideMask;
    #pragma unroll
    for (int m = 0; m < 8; ++m)
      #pragma unroll
      for (int j = 0; j < 4; ++j) {
        long grow = brow + wm * 128 + m * 16 + rb + j;
        float s = 0.f;
        #pragma unroll
        for (int n = 0; n < 4; ++n) {
          long gcol = bcol + wn * 64 + n * 16 + lr;
          float p = __expf(acc[m][n][j] * scale + mask[grow * ldc + gcol]);
          C[grow * ldc + gcol] = (f16)p;
          s += p;
        }
        s += __shfl_xor(s, 1);
        s += __shfl_xor(s, 2);
        s += __shfl_xor(s, 4);
        s += __shfl_xor(s, 8);
        if (lr == 0)
          lvec[((long)z * M + grow) * 32 + bx * 4 + wn] = s;
      }
  } else {
    float* C = (float*)Call + (long)z * strideC;
    #pragma unroll
    for (int m = 0; m < 8; ++m)
      #pragma unroll
      for (int j = 0; j < 4; ++j) {
        long grow = brow + wm * 128 + m * 16 + rb + j;
        float inv = 1.0f / lvec[(long)z * M + grow];
        #pragma unroll
        for (int n = 0; n < 4; ++n) {
          long gcol = bcol + wn * 64 + n * 16 + lr;
          C[grow * ldc + gcol] = acc[m][n][j] * inv;
        }
      }
  }
}

__global__ void reduce_l(const float* __restrict__ lpart, float* __restrict__ lsum, int n) {
  int i = blockIdx.x * blockDim.x + threadIdx.x;
  if (i < n) {
    float s = 0.f;
    #pragma unroll
    for (int j = 0; j < 32; ++j) s += lpart[(long)i * 32 + j];
    lsum[i] = s;
  }
}

extern "C" void kernel_launch(void* const* d_in, const int* in_sizes, int n_in,
                              void* d_out, int out_size, void* d_ws, size_t ws_size,
                              hipStream_t stream)
{
  const float* q    = (const float*)d_in[0];
  const float* k    = (const float*)d_in[1];
  const float* v    = (const float*)d_in[2];
  const float* mask = (const float*)d_in[3];
  const float* Wq   = (const float*)d_in[4];
  const float* Wk   = (const float*)d_in[5];
  const float* Wv   = (const float*)d_in[6];
  float* out = (float*)d_out;
  char*  ws  = (char*)d_ws;

  // workspace layout (bytes) — no aliasing now that cvt buffers are gone
  f16*   Pm    = (f16*)(ws + 0);           // 64 MB
  f16*   qp    = (f16*)(ws + 67108864);    // 32 MB
  f16*   kp    = (f16*)(ws + 100663296);   // 32 MB
  f16*   vpT   = (f16*)(ws + 134217728);   // 32 MB (stored H x J, transposed)
  float* lpart = (float*)(ws + 167772160); // 2 MB
  float* lsum  = (float*)(ws + 169869312); // 64 KB

  const long L = 2048, J = 2048, D = 1024, H = 1024;

  // 1) projections with fused fp32->fp16 (CVT staging)
  // qp[bl,h] = sum_d q[bl,d] * Wq[h,d]     M=16384 N=1024 K=1024
  gemm_bt<0, true><<<dim3(1024 / BN, 16384 / BM, 1), dim3(512), 0, stream>>>(
      q, Wq, qp, 16384, 1024, 1024, 1024, 1024, 1024,
      0, 0, 0, nullptr, 0, nullptr, 0.f);
  // kp[bj,h] = sum_d k[bj,d] * Wk[h,d]
  gemm_bt<0, true><<<dim3(1024 / BN, 16384 / BM, 1), dim3(512), 0, stream>>>(
      k, Wk, kp, 16384, 1024, 1024, 1024, 1024, 1024,
      0, 0, 0, nullptr, 0, nullptr, 0.f);
  // vpT[b][h,j] = sum_d Wv[h,d] * v[b][j,d]   M=1024 N=2048 K=1024, batched over b
  gemm_bt<0, true><<<dim3(2048 / BN, 1024 / BM, 8), dim3(512), 0, stream>>>(
      Wv, v, vpT, 1024, 2048, 1024, 1024, 1024, 2048,
      0, J * D, H * J, nullptr, 0, nullptr, 0.f);

  // 2) P[b][l,j] = exp(qp.kp^T / 32 + mask), fp16, + row-sum partials
  gemm_bt<1, false><<<dim3(2048 / BN, 2048 / BM, 8), dim3(512), 0, stream>>>(
      qp, kp, Pm, 2048, 2048, 1024, 1024, 1024, 2048,
      L * H, J * H, L * J, mask, L * J, lpart, 0.03125f);

  reduce_l<<<dim3(16384 / 256), dim3(256), 0, stream>>>(lpart, lsum, 16384);

  // 3) out[b][l,h] = (sum_j P[l,j] * vpT[h,j]) / l[b,l]   M=2048 N=1024 K=2048
  gemm_bt<2, false><<<dim3(1024 / BN, 2048 / BM, 8), dim3(512), 0, stream>>>(
      Pm, vpT, out, 2048, 1024, 2048, 2048, 2048, 1024,
      L * J, H * J, L * H, nullptr, 0, lsum, 0.f);
}